// Round 5
// baseline (434.948 us; speedup 1.0000x reference)
//
#include <hip/hip_runtime.h>
#include <stdint.h>

#define DM    1024
#define NH    16
#define HS    64
#define S_LEN 2048

typedef short bf16x8 __attribute__((ext_vector_type(8)));
typedef float f32x4  __attribute__((ext_vector_type(4)));
typedef unsigned short u16x4 __attribute__((ext_vector_type(4)));

__device__ __forceinline__ uint16_t f2b(float f) {
    union { float f; uint32_t i; } x; x.f = f;
    uint32_t r = x.i + 0x7fffu + ((x.i >> 16) & 1u);
    return (uint16_t)(r >> 16);
}
__device__ __forceinline__ uint32_t pack2(float a, float b) {
    return (uint32_t)f2b(a) | ((uint32_t)f2b(b) << 16);
}
__device__ __forceinline__ f32x4 mfma16(bf16x8 a, bf16x8 b, f32x4 c) {
    return __builtin_amdgcn_mfma_f32_16x16x32_bf16(a, b, c, 0, 0, 0);
}
// 16-lane-row max reduce step via DPP (VALU pipe, no LDS). CTRL must be an ICE,
// hence the template parameter (runtime arg does not compile).
template<int CTRL>
__device__ __forceinline__ float dpp_max(float x) {
    union { float f; int i; } u; u.f = x;
    int y = __builtin_amdgcn_update_dpp(u.i, u.i, CTRL, 0xF, 0xF, true);
    union { int i; float f; } v; v.i = y;
    return fmaxf(x, v.f);
}

// ---- One-time x (fp32) -> bf16 convert: 8 elems/thread ----
__global__ __launch_bounds__(256) void convert_bf16(
    const float* __restrict__ in, uint16_t* __restrict__ out)
{
    const size_t i = (size_t)blockIdx.x * 256 + threadIdx.x;
    const float4* p = (const float4*)in + i * 2;
    float4 a = p[0], b = p[1];
    uint4 o;
    o.x = pack2(a.x, a.y); o.y = pack2(a.z, a.w);
    o.z = pack2(b.x, b.y); o.w = pack2(b.z, b.w);
    ((uint4*)out)[i] = o;
}

// ---- One-time W (K=1024 x N fp32) -> WT (N x 1024 bf16) transpose ----
__global__ __launch_bounds__(256) void transpose_w(
    const float* __restrict__ W, uint16_t* __restrict__ WT, int N)
{
    __shared__ float T[32][33];
    const int tx = threadIdx.x & 31, ty = threadIdx.x >> 5;
    const int n0 = blockIdx.x * 32, k0 = blockIdx.y * 32;
    #pragma unroll
    for (int i = 0; i < 4; ++i)
        T[ty + i * 8][tx] = W[(size_t)(k0 + ty + i * 8) * N + n0 + tx];
    __syncthreads();
    #pragma unroll
    for (int i = 0; i < 4; ++i)
        WT[(size_t)(n0 + ty + i * 8) * 1024 + k0 + tx] = f2b(T[tx][ty + i * 8]);
}

// ---- MFMA GEMM: C(M x N) = A(M x 1024) @ BT^T + bias ----
// Double-buffered LDS (one barrier per k-step) + depth-2 register prefetch:
// iter t reads buf[t&1], issues loads for tile t+2, MFMAs, writes tile t+1
// into buf[(t+1)&1], single barrier. Hand-unrolled x2 so reg indices are static.
// MODE 0: N=3072 fused RoPE/split epilogue (WV: also emit V as bf16 [bh][hd][s]);
//         q pre-scaled by 0.125 (exact in bf16). MODE 1: plain fp32 out.
template<int MODE, bool ABF, bool WV>
__global__ __launch_bounds__(256) void gemm_mfma(
    const void* __restrict__ Araw,
    const uint16_t* __restrict__ BT,
    const float* __restrict__ bias,
    int N,
    const float* __restrict__ cq, const float* __restrict__ sq,
    const float* __restrict__ ck, const float* __restrict__ sk,
    uint16_t* __restrict__ qbuf, uint16_t* __restrict__ kbuf,
    float* __restrict__ kout, float* __restrict__ vout,
    uint16_t* __restrict__ vtb,
    float* __restrict__ Cout)
{
    __shared__ uint16_t As[2][128][40];
    __shared__ uint16_t Bs[2][128][40];

    const int tid  = threadIdx.x;
    const int wave = tid >> 6, lane = tid & 63;
    const int quad = lane >> 4, li = lane & 15;
    const int wm = (wave >> 1) * 64, wn = (wave & 1) * 64;
    const int m0 = blockIdx.y * 128, n0 = blockIdx.x * 128;

    f32x4 acc[4][4];
    #pragma unroll
    for (int a = 0; a < 4; ++a)
        #pragma unroll
        for (int c = 0; c < 4; ++c)
            acc[a][c] = (f32x4){0.f, 0.f, 0.f, 0.f};

    const int sm = tid >> 1, skc = (tid & 1) * 16;

    uint4 a0[2], b0[2], a1[2], b1[2];   // two register sets (tile parity)

    auto loadk = [&](int K0, uint4 (&AW)[2], uint4 (&BW)[2]) {
        if (ABF) {
            const uint16_t* ap = (const uint16_t*)Araw + (size_t)(m0 + sm) * 1024 + K0 + skc;
            AW[0] = *(const uint4*)ap;
            AW[1] = *(const uint4*)(ap + 8);
        } else {
            const float* ap = (const float*)Araw + (size_t)(m0 + sm) * 1024 + K0 + skc;
            float4 f0 = *(const float4*)(ap + 0),  f1 = *(const float4*)(ap + 4);
            float4 f2 = *(const float4*)(ap + 8),  f3 = *(const float4*)(ap + 12);
            AW[0].x = pack2(f0.x, f0.y); AW[0].y = pack2(f0.z, f0.w);
            AW[0].z = pack2(f1.x, f1.y); AW[0].w = pack2(f1.z, f1.w);
            AW[1].x = pack2(f2.x, f2.y); AW[1].y = pack2(f2.z, f2.w);
            AW[1].z = pack2(f3.x, f3.y); AW[1].w = pack2(f3.z, f3.w);
        }
        const uint16_t* bp = BT + (size_t)(n0 + sm) * 1024 + K0 + skc;
        BW[0] = *(const uint4*)bp;
        BW[1] = *(const uint4*)(bp + 8);
    };
    auto store = [&](int BUF, const uint4 (&AW)[2], const uint4 (&BW)[2]) {
        *(uint4*)&As[BUF][sm][skc]     = AW[0];
        *(uint4*)&As[BUF][sm][skc + 8] = AW[1];
        *(uint4*)&Bs[BUF][sm][skc]     = BW[0];
        *(uint4*)&Bs[BUF][sm][skc + 8] = BW[1];
    };
    auto compute = [&](int BUF) {
        bf16x8 af[4], bfr[4];
        #pragma unroll
        for (int mi = 0; mi < 4; ++mi)
            af[mi] = *(const bf16x8*)&As[BUF][wm + mi * 16 + li][quad * 8];
        #pragma unroll
        for (int ni = 0; ni < 4; ++ni)
            bfr[ni] = *(const bf16x8*)&Bs[BUF][wn + ni * 16 + li][quad * 8];
        #pragma unroll
        for (int mi = 0; mi < 4; ++mi)
            #pragma unroll
            for (int ni = 0; ni < 4; ++ni)
                acc[mi][ni] = mfma16(af[mi], bfr[ni], acc[mi][ni]);
    };

    // prologue: tile0 -> buf0, tile1 -> regset1
    loadk(0, a0, b0);
    store(0, a0, b0);
    loadk(32, a1, b1);
    __syncthreads();

    for (int t = 0; t < 32; t += 2) {
        const int kb = t * 32;
        // half A: buf0 holds tile t, regset1 holds tile t+1
        if (kb + 64 < 1024) loadk(kb + 64, a0, b0);    // tile t+2 (early issue)
        compute(0);
        store(1, a1, b1);                               // tile t+1 -> buf1
        __syncthreads();
        // half B: buf1 holds tile t+1, regset0 holds tile t+2
        if (kb + 96 < 1024) loadk(kb + 96, a1, b1);    // tile t+3
        compute(1);
        if (kb + 64 < 1024) {
            store(0, a0, b0);                           // tile t+2 -> buf0
            __syncthreads();
        }
    }

    if (MODE == 1) {
        #pragma unroll
        for (int ni = 0; ni < 4; ++ni) {
            const int n = n0 + wn + ni * 16 + li;
            const float bb = bias[n];
            #pragma unroll
            for (int mi = 0; mi < 4; ++mi)
                #pragma unroll
                for (int r = 0; r < 4; ++r) {
                    const int m = m0 + wm + mi * 16 + quad * 4 + r;
                    Cout[(size_t)m * N + n] = acc[mi][ni][r] + bb;
                }
        }
    } else {
        #pragma unroll
        for (int ni = 0; ni < 4; ++ni) {
            const int n   = n0 + wn + ni * 16 + li;
            const int sel = n >> 10;        // 0=q 1=k 2=v (wave-uniform per ni)
            const int d   = n & 1023;
            const int h   = d >> 6;
            const int hd  = d & 63;
            const int i0  = hd >> 1;
            const float bb = bias[n];
            #pragma unroll
            for (int mi = 0; mi < 4; ++mi) {
                const int mb = m0 + wm + mi * 16 + quad * 4;
                const int b  = mb >> 11;
                const int s0 = mb & 2047;
                float vv[4];
                #pragma unroll
                for (int r = 0; r < 4; ++r) {
                    const int s = s0 + r;
                    const float val  = acc[mi][ni][r] + bb;
                    const float part = __shfl_xor(val, 1);   // RoPE partner (n^1)
                    const size_t idx = ((size_t)(b * NH + h) * S_LEN + s) * HS + hd;
                    if (sel == 0) {
                        float c = cq[s * 32 + i0], sn = sq[s * 32 + i0];
                        float o = (hd & 1) ? (part * sn + val * c) : (val * c - part * sn);
                        qbuf[idx] = f2b(o * 0.125f);         // fold 1/sqrt(HS), exact
                    } else if (sel == 1) {
                        kout[idx] = val;                     // kv[0] = pre-rotary k
                        float c = ck[s * 32 + i0], sn = sk[s * 32 + i0];
                        float o = (hd & 1) ? (part * sn + val * c) : (val * c - part * sn);
                        kbuf[idx] = f2b(o);
                    } else {
                        vout[idx] = val;                     // kv[1] = v
                        vv[r] = val;
                    }
                }
                if (WV && sel == 2) {
                    u16x4 u;
                    u[0] = f2b(vv[0]); u[1] = f2b(vv[1]);
                    u[2] = f2b(vv[2]); u[3] = f2b(vv[3]);
                    *(u16x4*)&vtb[((size_t)(b * NH + h) * HS + hd) * S_LEN + s0] = u;
                }
            }
        }
    }
}

// ---- MFMA flash attention: block = (b,h) x 64-query tile, 4 waves x 16 rows ----
// V pre-transposed bf16 [bh][hd][s]. Q fragments loaded direct from global (no Qs LDS).
// Softmax: row-max via DPP (no DS pipe), row-sum via MFMA with ones-B (C-layout match).
__global__ __launch_bounds__(256) void attn_mfma(
    const uint16_t* __restrict__ qbuf,
    const uint16_t* __restrict__ kbuf,
    const uint16_t* __restrict__ vtb,
    uint16_t* __restrict__ obuf)
{
    __shared__ uint16_t Ks[64][72];
    __shared__ uint16_t Vt[64][72];   // [hs][key]
    __shared__ uint16_t Ps[64][68];   // stride 68 (34 dw): conflict-free writes+reads

    const int i  = blockIdx.x;
    const int bh = i >> 5;
    const int jj = i & 31;
    const int g  = jj >> 3, cc = jj & 7;
    const int qt = (g == 0) ? (31 - cc) : (g == 1) ? cc : (g == 2) ? (23 - cc) : (8 + cc);
    const int h = bh & 15, b = bh >> 4;
    const int tid = threadIdx.x;
    const int wave = tid >> 6, lane = tid & 63;
    const int quad = lane >> 4, li = lane & 15;
    const int wrow0 = wave * 16;

    const short onebf = (short)0x3F80;   // bf16 1.0
    const bf16x8 kOnes = {onebf, onebf, onebf, onebf, onebf, onebf, onebf, onebf};

    // Q fragments direct from global: lane reads rows wrow0+li, cols quad*8(+32)
    const uint16_t* qp = qbuf + ((size_t)bh * S_LEN + qt * 64 + wrow0 + li) * HS + quad * 8;
    const bf16x8 aq0 = *(const bf16x8*)qp;
    const bf16x8 aq1 = *(const bf16x8*)(qp + 32);

    f32x4 oacc[4];
    float m_i[4], l_i[4];
    #pragma unroll
    for (int r = 0; r < 4; ++r) {
        m_i[r] = -1e30f; l_i[r] = 0.f;
        oacc[r] = (f32x4){0.f, 0.f, 0.f, 0.f};
    }

    const int row = tid >> 2, c = (tid & 3) * 16;         // shared staging coords
    uint4 kr0, kr1, vr0, vr1;

    auto load_kv = [&](int kt) {
        const uint16_t* kp = kbuf + ((size_t)bh * S_LEN + kt * 64 + row) * HS + c;
        kr0 = *(const uint4*)kp;
        kr1 = *(const uint4*)(kp + 8);
        const uint16_t* vp = vtb + ((size_t)bh * HS + row) * S_LEN + kt * 64 + c;
        vr0 = *(const uint4*)vp;
        vr1 = *(const uint4*)(vp + 8);
    };
    load_kv(0);

    for (int kt = 0; kt <= qt; ++kt) {
        __syncthreads();   // previous tile's LDS consumers done
        *(uint4*)&Ks[row][c]     = kr0;
        *(uint4*)&Ks[row][c + 8] = kr1;
        *(uint4*)&Vt[row][c]     = vr0;
        *(uint4*)&Vt[row][c + 8] = vr1;
        __syncthreads();
        if (kt < qt) load_kv(kt + 1);   // prefetch next tile under compute

        // S = Q K^T  (wave's 16 rows x 64 keys); q pre-scaled by 1/sqrt(HS)
        f32x4 sacc[4];
        __builtin_amdgcn_s_setprio(1);
        #pragma unroll
        for (int ni = 0; ni < 4; ++ni) {
            bf16x8 b0 = *(const bf16x8*)&Ks[ni * 16 + li][quad * 8];
            bf16x8 b1 = *(const bf16x8*)&Ks[ni * 16 + li][32 + quad * 8];
            f32x4 z = (f32x4){0.f, 0.f, 0.f, 0.f};
            z = mfma16(aq0, b0, z);
            sacc[ni] = mfma16(aq1, b1, z);
        }
        __builtin_amdgcn_s_setprio(0);

        // online softmax (C-layout: row = quad*4+r, col = ni*16+li)
        const bool diag = (kt == qt);
        float p[4][4];
        #pragma unroll
        for (int ni = 0; ni < 4; ++ni)
            #pragma unroll
            for (int r = 0; r < 4; ++r) {
                float v = sacc[ni][r];
                if (diag && (ni * 16 + li > wrow0 + quad * 4 + r)) v = -65504.f;
                p[ni][r] = v;
            }
        float alp[4];
        #pragma unroll
        for (int r = 0; r < 4; ++r) {
            float mx = fmaxf(fmaxf(p[0][r], p[1][r]), fmaxf(p[2][r], p[3][r]));
            mx = dpp_max<0xB1>(mx);    // quad_perm [1,0,3,2]  (xor 1)
            mx = dpp_max<0x4E>(mx);    // quad_perm [2,3,0,1]  (xor 2)
            mx = dpp_max<0x124>(mx);   // row_ror:4
            mx = dpp_max<0x128>(mx);   // row_ror:8  -> all-16-lane max
            float mnew  = fmaxf(m_i[r], mx);
            alp[r] = __expf(m_i[r] - mnew);
            m_i[r] = mnew;
            #pragma unroll
            for (int ni = 0; ni < 4; ++ni)
                p[ni][r] = __expf(p[ni][r] - mnew);
            #pragma unroll
            for (int ni = 0; ni < 4; ++ni) oacc[ni][r] *= alp[r];
        }

        // P: C-layout -> A-layout via wave-private LDS slab
        #pragma unroll
        for (int ni = 0; ni < 4; ++ni)
            #pragma unroll
            for (int r = 0; r < 4; ++r)
                Ps[wrow0 + quad * 4 + r][ni * 16 + li] = f2b(p[ni][r]);

        bf16x8 pa0 = *(const bf16x8*)&Ps[wrow0 + li][quad * 8];
        bf16x8 pa1 = *(const bf16x8*)&Ps[wrow0 + li][32 + quad * 8];

        // row-sum via MFMA with B=ones: ls[r] lands in same per-lane slot as sacc
        __builtin_amdgcn_s_setprio(1);
        f32x4 ls = (f32x4){0.f, 0.f, 0.f, 0.f};
        ls = mfma16(pa0, kOnes, ls);
        ls = mfma16(pa1, kOnes, ls);

        // O += P @ V
        #pragma unroll
        for (int ni = 0; ni < 4; ++ni) {
            bf16x8 v0 = *(const bf16x8*)&Vt[ni * 16 + li][quad * 8];
            bf16x8 v1 = *(const bf16x8*)&Vt[ni * 16 + li][32 + quad * 8];
            oacc[ni] = mfma16(pa0, v0, oacc[ni]);
            oacc[ni] = mfma16(pa1, v1, oacc[ni]);
        }
        __builtin_amdgcn_s_setprio(0);

        #pragma unroll
        for (int r = 0; r < 4; ++r)
            l_i[r] = l_i[r] * alp[r] + ls[r];
    }

    #pragma unroll
    for (int ni = 0; ni < 4; ++ni)
        #pragma unroll
        for (int r = 0; r < 4; ++r) {
            const int qg = qt * 64 + wrow0 + quad * 4 + r;
            obuf[((size_t)b * S_LEN + qg) * DM + h * HS + ni * 16 + li] =
                f2b(oacc[ni][r] / l_i[r]);
        }
}

extern "C" void kernel_launch(void* const* d_in, const int* in_sizes, int n_in,
                              void* d_out, int out_size, void* d_ws, size_t ws_size,
                              hipStream_t stream) {
    const float* x  = (const float*)d_in[0];
    const float* cq = (const float*)d_in[1];
    const float* sq = (const float*)d_in[2];
    const float* ck = (const float*)d_in[3];
    const float* sk = (const float*)d_in[4];
    // d_in[5]: causal tril mask (int32) — structure known, not re-read
    const float* Wp = (const float*)d_in[6];
    const float* bp = (const float*)d_in[7];
    const float* Wf = (const float*)d_in[8];
    const float* bf = (const float*)d_in[9];

    float* out  = (float*)d_out;
    float* ffo  = out;                 // (B,S,DM) fp32
    float* kout = out + 4194304;       // kv[0] = pre-rotary k (B,NH,S,HS) fp32
    float* vout = out + 8388608;       // kv[1] = v fp32

    uint16_t* qbuf = (uint16_t*)d_ws;  // RoPE'd q bf16 (pre-scaled)    [0,8M)
    uint16_t* kbuf = qbuf + 4194304;   // RoPE'd k bf16                 [8M,16M)
    uint16_t* abuf = kbuf + 4194304;   // attn_o bf16                   [16M,24M)
    uint16_t* vtb  = abuf + 4194304;   // V bf16 [bh][hd][s]            [24M,32M)
    uint16_t* xbf  = vtb  + 4194304;   // x bf16                        [32M,40M)
    uint16_t* WpT  = abuf;             // alias: dead before attn writes abuf
    uint16_t* WfT  = qbuf;             // alias: qbuf dead after attn

    const bool has_xbf = ws_size >= (size_t)40 * 1024 * 1024;

    dim3 blk(256);
    transpose_w<<<dim3(96, 32), blk, 0, stream>>>(Wp, WpT, 3072);
    if (has_xbf) {
        convert_bf16<<<dim3(2048), blk, 0, stream>>>(x, xbf);
        gemm_mfma<0, true, true><<<dim3(24, 32), blk, 0, stream>>>(
            xbf, WpT, bp, 3072, cq, sq, ck, sk,
            qbuf, kbuf, kout, vout, vtb, nullptr);
    } else {
        gemm_mfma<0, false, true><<<dim3(24, 32), blk, 0, stream>>>(
            x, WpT, bp, 3072, cq, sq, ck, sk,
            qbuf, kbuf, kout, vout, vtb, nullptr);
    }
    attn_mfma<<<dim3(1024), blk, 0, stream>>>(qbuf, kbuf, vtb, abuf);
    transpose_w<<<dim3(32, 32), blk, 0, stream>>>(Wf, WfT, 1024);
    gemm_mfma<1, true, false><<<dim3(8, 32), blk, 0, stream>>>(
        abuf, WfT, bf, 1024, nullptr, nullptr, nullptr, nullptr,
        nullptr, nullptr, nullptr, nullptr, nullptr, ffo);
}

// Round 6
// 291.933 us; speedup vs baseline: 1.4899x; 1.4899x over previous
//
#include <hip/hip_runtime.h>
#include <stdint.h>

#define DM    1024
#define NH    16
#define HS    64
#define S_LEN 2048

typedef short bf16x8 __attribute__((ext_vector_type(8)));
typedef float f32x4  __attribute__((ext_vector_type(4)));
typedef unsigned short u16x4 __attribute__((ext_vector_type(4)));

__device__ __forceinline__ uint16_t f2b(float f) {
    union { float f; uint32_t i; } x; x.f = f;
    uint32_t r = x.i + 0x7fffu + ((x.i >> 16) & 1u);
    return (uint16_t)(r >> 16);
}
__device__ __forceinline__ uint32_t pack2(float a, float b) {
    return (uint32_t)f2b(a) | ((uint32_t)f2b(b) << 16);
}
__device__ __forceinline__ f32x4 mfma16(bf16x8 a, bf16x8 b, f32x4 c) {
    return __builtin_amdgcn_mfma_f32_16x16x32_bf16(a, b, c, 0, 0, 0);
}
// 16-lane-row max reduce step via DPP (VALU pipe, no LDS). CTRL must be an ICE.
template<int CTRL>
__device__ __forceinline__ float dpp_max(float x) {
    union { float f; int i; } u; u.f = x;
    int y = __builtin_amdgcn_update_dpp(u.i, u.i, CTRL, 0xF, 0xF, true);
    union { int i; float f; } v; v.i = y;
    return fmaxf(x, v.f);
}

// ---- One-time x (fp32) -> bf16 convert: 8 elems/thread ----
__global__ __launch_bounds__(256) void convert_bf16(
    const float* __restrict__ in, uint16_t* __restrict__ out)
{
    const size_t i = (size_t)blockIdx.x * 256 + threadIdx.x;
    const float4* p = (const float4*)in + i * 2;
    float4 a = p[0], b = p[1];
    uint4 o;
    o.x = pack2(a.x, a.y); o.y = pack2(a.z, a.w);
    o.z = pack2(b.x, b.y); o.w = pack2(b.z, b.w);
    ((uint4*)out)[i] = o;
}

// ---- One-time W (K=1024 x N fp32) -> WT (N x 1024 bf16) transpose ----
__global__ __launch_bounds__(256) void transpose_w(
    const float* __restrict__ W, uint16_t* __restrict__ WT, int N)
{
    __shared__ float T[32][33];
    const int tx = threadIdx.x & 31, ty = threadIdx.x >> 5;
    const int n0 = blockIdx.x * 32, k0 = blockIdx.y * 32;
    #pragma unroll
    for (int i = 0; i < 4; ++i)
        T[ty + i * 8][tx] = W[(size_t)(k0 + ty + i * 8) * N + n0 + tx];
    __syncthreads();
    #pragma unroll
    for (int i = 0; i < 4; ++i)
        WT[(size_t)(n0 + ty + i * 8) * 1024 + k0 + tx] = f2b(T[tx][ty + i * 8]);
}

// Staging register macros: NAMED SCALARS ONLY (no arrays across statements, no
// reference params) — R5's lambda-&-array version put the sets in scratch
// (+253 MB writes/dispatch). All LDS buffer indices are literals.
#define LOADK(K0, A0_, A1_, B0_, B1_)                                                      \
    do {                                                                                   \
        if (ABF) {                                                                         \
            const uint16_t* ap_ = (const uint16_t*)Araw + (size_t)(m0 + sm) * 1024 + (K0) + skc; \
            A0_ = *(const uint4*)ap_;                                                      \
            A1_ = *(const uint4*)(ap_ + 8);                                                \
        } else {                                                                           \
            const float* ap_ = (const float*)Araw + (size_t)(m0 + sm) * 1024 + (K0) + skc; \
            float4 f0_ = *(const float4*)(ap_ + 0),  f1_ = *(const float4*)(ap_ + 4);      \
            float4 f2_ = *(const float4*)(ap_ + 8),  f3_ = *(const float4*)(ap_ + 12);     \
            A0_.x = pack2(f0_.x, f0_.y); A0_.y = pack2(f0_.z, f0_.w);                      \
            A0_.z = pack2(f1_.x, f1_.y); A0_.w = pack2(f1_.z, f1_.w);                      \
            A1_.x = pack2(f2_.x, f2_.y); A1_.y = pack2(f2_.z, f2_.w);                      \
            A1_.z = pack2(f3_.x, f3_.y); A1_.w = pack2(f3_.z, f3_.w);                      \
        }                                                                                  \
        const uint16_t* bp_ = BT + (size_t)(n0 + sm) * 1024 + (K0) + skc;                  \
        B0_ = *(const uint4*)bp_;                                                          \
        B1_ = *(const uint4*)(bp_ + 8);                                                    \
    } while (0)

#define STOREK(BUF, A0_, A1_, B0_, B1_)                                                    \
    do {                                                                                   \
        *(uint4*)&As[BUF][sm][skc]     = A0_;                                              \
        *(uint4*)&As[BUF][sm][skc + 8] = A1_;                                              \
        *(uint4*)&Bs[BUF][sm][skc]     = B0_;                                              \
        *(uint4*)&Bs[BUF][sm][skc + 8] = B1_;                                              \
    } while (0)

#define COMPUTEK(BUF)                                                                      \
    do {                                                                                   \
        bf16x8 af_[4], bf_[4];                                                             \
        _Pragma("unroll")                                                                  \
        for (int mi = 0; mi < 4; ++mi)                                                     \
            af_[mi] = *(const bf16x8*)&As[BUF][wm + mi * 16 + li][quad * 8];               \
        _Pragma("unroll")                                                                  \
        for (int ni = 0; ni < 4; ++ni)                                                     \
            bf_[ni] = *(const bf16x8*)&Bs[BUF][wn + ni * 16 + li][quad * 8];               \
        _Pragma("unroll")                                                                  \
        for (int mi = 0; mi < 4; ++mi)                                                     \
            _Pragma("unroll")                                                              \
            for (int ni = 0; ni < 4; ++ni)                                                 \
                acc[mi][ni] = mfma16(af_[mi], bf_[ni], acc[mi][ni]);                       \
    } while (0)

// ---- MFMA GEMM: C(M x N) = A(M x 1024) @ BT^T + bias ----
// Double-buffered LDS, one barrier per k-step, depth-2 register prefetch.
// MODE 0: N=3072 fused RoPE/split epilogue (WV: also emit V as bf16 [bh][hd][s]);
//         q pre-scaled by 0.125 (exact in bf16). MODE 1: plain fp32 out.
template<int MODE, bool ABF, bool WV>
__global__ __launch_bounds__(256) void gemm_mfma(
    const void* __restrict__ Araw,
    const uint16_t* __restrict__ BT,
    const float* __restrict__ bias,
    int N,
    const float* __restrict__ cq, const float* __restrict__ sq,
    const float* __restrict__ ck, const float* __restrict__ sk,
    uint16_t* __restrict__ qbuf, uint16_t* __restrict__ kbuf,
    float* __restrict__ kout, float* __restrict__ vout,
    uint16_t* __restrict__ vtb,
    float* __restrict__ Cout)
{
    __shared__ uint16_t As[2][128][40];
    __shared__ uint16_t Bs[2][128][40];

    const int tid  = threadIdx.x;
    const int wave = tid >> 6, lane = tid & 63;
    const int quad = lane >> 4, li = lane & 15;
    const int wm = (wave >> 1) * 64, wn = (wave & 1) * 64;
    const int m0 = blockIdx.y * 128, n0 = blockIdx.x * 128;

    f32x4 acc[4][4];
    #pragma unroll
    for (int a = 0; a < 4; ++a)
        #pragma unroll
        for (int c = 0; c < 4; ++c)
            acc[a][c] = (f32x4){0.f, 0.f, 0.f, 0.f};

    const int sm = tid >> 1, skc = (tid & 1) * 16;

    // two named register sets (tile parity) — stay in VGPRs
    uint4 Aa0, Aa1, Ba0, Ba1;
    uint4 Ab0, Ab1, Bb0, Bb1;

    // prologue: tile0 -> buf0, tile1 -> parity-1 regs
    LOADK(0, Aa0, Aa1, Ba0, Ba1);
    STOREK(0, Aa0, Aa1, Ba0, Ba1);
    LOADK(32, Ab0, Ab1, Bb0, Bb1);
    __syncthreads();

    for (int t = 0; t < 16; ++t) {
        const int kb = t * 64;
        // half A: buf0 = tile 2t, parity-1 regs = tile 2t+1
        if (t < 15) LOADK(kb + 64, Aa0, Aa1, Ba0, Ba1);   // tile 2t+2, early issue
        COMPUTEK(0);
        STOREK(1, Ab0, Ab1, Bb0, Bb1);                     // tile 2t+1 -> buf1
        __syncthreads();
        // half B: buf1 = tile 2t+1, parity-0 regs = tile 2t+2
        if (t < 15) LOADK(kb + 96, Ab0, Ab1, Bb0, Bb1);   // tile 2t+3
        COMPUTEK(1);
        if (t < 15) {
            STOREK(0, Aa0, Aa1, Ba0, Ba1);                 // tile 2t+2 -> buf0
            __syncthreads();
        }
    }

    if (MODE == 1) {
        #pragma unroll
        for (int ni = 0; ni < 4; ++ni) {
            const int n = n0 + wn + ni * 16 + li;
            const float bb = bias[n];
            #pragma unroll
            for (int mi = 0; mi < 4; ++mi)
                #pragma unroll
                for (int r = 0; r < 4; ++r) {
                    const int m = m0 + wm + mi * 16 + quad * 4 + r;
                    Cout[(size_t)m * N + n] = acc[mi][ni][r] + bb;
                }
        }
    } else {
        #pragma unroll
        for (int ni = 0; ni < 4; ++ni) {
            const int n   = n0 + wn + ni * 16 + li;
            const int sel = n >> 10;        // 0=q 1=k 2=v (wave-uniform per ni)
            const int d   = n & 1023;
            const int h   = d >> 6;
            const int hd  = d & 63;
            const int i0  = hd >> 1;
            const float bb = bias[n];
            #pragma unroll
            for (int mi = 0; mi < 4; ++mi) {
                const int mb = m0 + wm + mi * 16 + quad * 4;
                const int b  = mb >> 11;
                const int s0 = mb & 2047;
                float vv[4];
                #pragma unroll
                for (int r = 0; r < 4; ++r) {
                    const int s = s0 + r;
                    const float val  = acc[mi][ni][r] + bb;
                    const float part = __shfl_xor(val, 1);   // RoPE partner (n^1)
                    const size_t idx = ((size_t)(b * NH + h) * S_LEN + s) * HS + hd;
                    if (sel == 0) {
                        float c = cq[s * 32 + i0], sn = sq[s * 32 + i0];
                        float o = (hd & 1) ? (part * sn + val * c) : (val * c - part * sn);
                        qbuf[idx] = f2b(o * 0.125f);         // fold 1/sqrt(HS), exact
                    } else if (sel == 1) {
                        kout[idx] = val;                     // kv[0] = pre-rotary k
                        float c = ck[s * 32 + i0], sn = sk[s * 32 + i0];
                        float o = (hd & 1) ? (part * sn + val * c) : (val * c - part * sn);
                        kbuf[idx] = f2b(o);
                    } else {
                        vout[idx] = val;                     // kv[1] = v
                        vv[r] = val;
                    }
                }
                if (WV && sel == 2) {
                    u16x4 u;
                    u[0] = f2b(vv[0]); u[1] = f2b(vv[1]);
                    u[2] = f2b(vv[2]); u[3] = f2b(vv[3]);
                    *(u16x4*)&vtb[((size_t)(b * NH + h) * HS + hd) * S_LEN + s0] = u;
                }
            }
        }
    }
}

// ---- MFMA flash attention: block = (b,h) x 64-query tile, 4 waves x 16 rows ----
// V pre-transposed bf16 [bh][hd][s]. Q fragments loaded direct from global (no Qs LDS).
// Softmax: row-max via DPP (no DS pipe), row-sum via MFMA with ones-B (C-layout match).
__global__ __launch_bounds__(256) void attn_mfma(
    const uint16_t* __restrict__ qbuf,
    const uint16_t* __restrict__ kbuf,
    const uint16_t* __restrict__ vtb,
    uint16_t* __restrict__ obuf)
{
    __shared__ uint16_t Ks[64][72];
    __shared__ uint16_t Vt[64][72];   // [hs][key]
    __shared__ uint16_t Ps[64][68];   // stride 68 (34 dw): conflict-free writes+reads

    const int i  = blockIdx.x;
    const int bh = i >> 5;
    const int jj = i & 31;
    const int g  = jj >> 3, cc = jj & 7;
    const int qt = (g == 0) ? (31 - cc) : (g == 1) ? cc : (g == 2) ? (23 - cc) : (8 + cc);
    const int h = bh & 15, b = bh >> 4;
    const int tid = threadIdx.x;
    const int wave = tid >> 6, lane = tid & 63;
    const int quad = lane >> 4, li = lane & 15;
    const int wrow0 = wave * 16;

    const short onebf = (short)0x3F80;   // bf16 1.0
    const bf16x8 kOnes = {onebf, onebf, onebf, onebf, onebf, onebf, onebf, onebf};

    // Q fragments direct from global: lane reads rows wrow0+li, cols quad*8(+32)
    const uint16_t* qp = qbuf + ((size_t)bh * S_LEN + qt * 64 + wrow0 + li) * HS + quad * 8;
    const bf16x8 aq0 = *(const bf16x8*)qp;
    const bf16x8 aq1 = *(const bf16x8*)(qp + 32);

    f32x4 oacc[4];
    float m_i[4], l_i[4];
    #pragma unroll
    for (int r = 0; r < 4; ++r) {
        m_i[r] = -1e30f; l_i[r] = 0.f;
        oacc[r] = (f32x4){0.f, 0.f, 0.f, 0.f};
    }

    const int row = tid >> 2, c = (tid & 3) * 16;         // shared staging coords
    uint4 kr0, kr1, vr0, vr1;

    auto load_kv = [&](int kt) {
        const uint16_t* kp = kbuf + ((size_t)bh * S_LEN + kt * 64 + row) * HS + c;
        kr0 = *(const uint4*)kp;
        kr1 = *(const uint4*)(kp + 8);
        const uint16_t* vp = vtb + ((size_t)bh * HS + row) * S_LEN + kt * 64 + c;
        vr0 = *(const uint4*)vp;
        vr1 = *(const uint4*)(vp + 8);
    };
    load_kv(0);

    for (int kt = 0; kt <= qt; ++kt) {
        __syncthreads();   // previous tile's LDS consumers done
        *(uint4*)&Ks[row][c]     = kr0;
        *(uint4*)&Ks[row][c + 8] = kr1;
        *(uint4*)&Vt[row][c]     = vr0;
        *(uint4*)&Vt[row][c + 8] = vr1;
        __syncthreads();
        if (kt < qt) load_kv(kt + 1);   // prefetch next tile under compute

        // S = Q K^T  (wave's 16 rows x 64 keys); q pre-scaled by 1/sqrt(HS)
        f32x4 sacc[4];
        __builtin_amdgcn_s_setprio(1);
        #pragma unroll
        for (int ni = 0; ni < 4; ++ni) {
            bf16x8 b0 = *(const bf16x8*)&Ks[ni * 16 + li][quad * 8];
            bf16x8 b1 = *(const bf16x8*)&Ks[ni * 16 + li][32 + quad * 8];
            f32x4 z = (f32x4){0.f, 0.f, 0.f, 0.f};
            z = mfma16(aq0, b0, z);
            sacc[ni] = mfma16(aq1, b1, z);
        }
        __builtin_amdgcn_s_setprio(0);

        // online softmax (C-layout: row = quad*4+r, col = ni*16+li)
        const bool diag = (kt == qt);
        float p[4][4];
        #pragma unroll
        for (int ni = 0; ni < 4; ++ni)
            #pragma unroll
            for (int r = 0; r < 4; ++r) {
                float v = sacc[ni][r];
                if (diag && (ni * 16 + li > wrow0 + quad * 4 + r)) v = -65504.f;
                p[ni][r] = v;
            }
        float alp[4];
        #pragma unroll
        for (int r = 0; r < 4; ++r) {
            float mx = fmaxf(fmaxf(p[0][r], p[1][r]), fmaxf(p[2][r], p[3][r]));
            mx = dpp_max<0xB1>(mx);    // quad_perm [1,0,3,2]  (xor 1)
            mx = dpp_max<0x4E>(mx);    // quad_perm [2,3,0,1]  (xor 2)
            mx = dpp_max<0x124>(mx);   // row_ror:4
            mx = dpp_max<0x128>(mx);   // row_ror:8  -> all-16-lane max
            float mnew  = fmaxf(m_i[r], mx);
            alp[r] = __expf(m_i[r] - mnew);
            m_i[r] = mnew;
            #pragma unroll
            for (int ni = 0; ni < 4; ++ni)
                p[ni][r] = __expf(p[ni][r] - mnew);
            #pragma unroll
            for (int ni = 0; ni < 4; ++ni) oacc[ni][r] *= alp[r];
        }

        // P: C-layout -> A-layout via wave-private LDS slab
        #pragma unroll
        for (int ni = 0; ni < 4; ++ni)
            #pragma unroll
            for (int r = 0; r < 4; ++r)
                Ps[wrow0 + quad * 4 + r][ni * 16 + li] = f2b(p[ni][r]);

        bf16x8 pa0 = *(const bf16x8*)&Ps[wrow0 + li][quad * 8];
        bf16x8 pa1 = *(const bf16x8*)&Ps[wrow0 + li][32 + quad * 8];

        // row-sum via MFMA with B=ones: ls[r] lands in same per-lane slot as sacc
        __builtin_amdgcn_s_setprio(1);
        f32x4 ls = (f32x4){0.f, 0.f, 0.f, 0.f};
        ls = mfma16(pa0, kOnes, ls);
        ls = mfma16(pa1, kOnes, ls);

        // O += P @ V
        #pragma unroll
        for (int ni = 0; ni < 4; ++ni) {
            bf16x8 v0 = *(const bf16x8*)&Vt[ni * 16 + li][quad * 8];
            bf16x8 v1 = *(const bf16x8*)&Vt[ni * 16 + li][32 + quad * 8];
            oacc[ni] = mfma16(pa0, v0, oacc[ni]);
            oacc[ni] = mfma16(pa1, v1, oacc[ni]);
        }
        __builtin_amdgcn_s_setprio(0);

        #pragma unroll
        for (int r = 0; r < 4; ++r)
            l_i[r] = l_i[r] * alp[r] + ls[r];
    }

    #pragma unroll
    for (int ni = 0; ni < 4; ++ni)
        #pragma unroll
        for (int r = 0; r < 4; ++r) {
            const int qg = qt * 64 + wrow0 + quad * 4 + r;
            obuf[((size_t)b * S_LEN + qg) * DM + h * HS + ni * 16 + li] =
                f2b(oacc[ni][r] / l_i[r]);
        }
}

extern "C" void kernel_launch(void* const* d_in, const int* in_sizes, int n_in,
                              void* d_out, int out_size, void* d_ws, size_t ws_size,
                              hipStream_t stream) {
    const float* x  = (const float*)d_in[0];
    const float* cq = (const float*)d_in[1];
    const float* sq = (const float*)d_in[2];
    const float* ck = (const float*)d_in[3];
    const float* sk = (const float*)d_in[4];
    // d_in[5]: causal tril mask (int32) — structure known, not re-read
    const float* Wp = (const float*)d_in[6];
    const float* bp = (const float*)d_in[7];
    const float* Wf = (const float*)d_in[8];
    const float* bf = (const float*)d_in[9];

    float* out  = (float*)d_out;
    float* ffo  = out;                 // (B,S,DM) fp32
    float* kout = out + 4194304;       // kv[0] = pre-rotary k (B,NH,S,HS) fp32
    float* vout = out + 8388608;       // kv[1] = v fp32

    uint16_t* qbuf = (uint16_t*)d_ws;  // RoPE'd q bf16 (pre-scaled)    [0,8M)
    uint16_t* kbuf = qbuf + 4194304;   // RoPE'd k bf16                 [8M,16M)
    uint16_t* abuf = kbuf + 4194304;   // attn_o bf16                   [16M,24M)
    uint16_t* vtb  = abuf + 4194304;   // V bf16 [bh][hd][s]            [24M,32M)
    uint16_t* xbf  = vtb  + 4194304;   // x bf16                        [32M,40M)
    uint16_t* WpT  = abuf;             // alias: dead before attn writes abuf
    uint16_t* WfT  = qbuf;             // alias: qbuf dead after attn

    const bool has_xbf = ws_size >= (size_t)40 * 1024 * 1024;

    dim3 blk(256);
    transpose_w<<<dim3(96, 32), blk, 0, stream>>>(Wp, WpT, 3072);
    if (has_xbf) {
        convert_bf16<<<dim3(2048), blk, 0, stream>>>(x, xbf);
        gemm_mfma<0, true, true><<<dim3(24, 32), blk, 0, stream>>>(
            xbf, WpT, bp, 3072, cq, sq, ck, sk,
            qbuf, kbuf, kout, vout, vtb, nullptr);
    } else {
        gemm_mfma<0, false, true><<<dim3(24, 32), blk, 0, stream>>>(
            x, WpT, bp, 3072, cq, sq, ck, sk,
            qbuf, kbuf, kout, vout, vtb, nullptr);
    }
    attn_mfma<<<dim3(1024), blk, 0, stream>>>(qbuf, kbuf, vtb, abuf);
    transpose_w<<<dim3(32, 32), blk, 0, stream>>>(Wf, WfT, 1024);
    gemm_mfma<1, true, false><<<dim3(8, 32), blk, 0, stream>>>(
        abuf, WfT, bf, 1024, nullptr, nullptr, nullptr, nullptr,
        nullptr, nullptr, nullptr, nullptr, nullptr, ffo);
}